// Round 14
// baseline (139.786 us; speedup 1.0000x reference)
//
#include <hip/hip_runtime.h>

// VectorQuantizer: B=16, D=64, H=64, W=64, K=1024
#define DD 64
#define KK 1024
#define NPTS 65536
#define TOTAL 4194304
#define NBLK_TOTAL 512   // ticket: A(256) + B(256)

// Output layout (flat f32): quantized[4194304], L1, L2, idx[65536]
#define OFF_L1 4194304
#define OFF_L2 4194305
#define OFF_IDX 4194306

// ws layout (bytes): [0] f32 sum, [8] u32 ticket, enh @ float 64 (byte 256),
// ehT @ byte 65536 (128KB), elT @ byte 196608 (128KB). (<=328KB used)
#define WS_ENH_F 64
#define WS_EHT_BYTE 65536
#define WS_ELT_BYTE (65536 + 131072)

// score = dot(x,e) + 512 - ||e||^2/2  (argmax == argmin distance).
// Rescue margin: 64-ulp granule (<=4.6e-3) + bf16x3 err (~6e-4) + slack.
#define MARGIN_S 0.008f

typedef __attribute__((ext_vector_type(8))) short short8;
typedef __attribute__((ext_vector_type(4))) float f32x4;

__device__ __forceinline__ unsigned short bf16_rne(float f) {
    unsigned b = __float_as_uint(f);
    return (unsigned short)((b + 0x7FFFu + ((b >> 16) & 1u)) >> 16);
}
__device__ __forceinline__ float bf16_to_f(unsigned short h) {
    return __uint_as_float(((unsigned)h) << 16);
}
__device__ __forceinline__ unsigned umax(unsigned a, unsigned b) { return a > b ? a : b; }
__device__ __forceinline__ unsigned umin(unsigned a, unsigned b) { return a < b ? a : b; }
// async global->LDS DMA, 16B per lane; LDS dest = wave-uniform base + lane*16
__device__ __forceinline__ void gld_lds16(const void* g, void* l) {
    __builtin_amdgcn_global_load_lds(
        (const __attribute__((address_space(1))) void*)g,
        (__attribute__((address_space(3))) void*)l, 16, 0, 0);
}
// swizzled position of element d within a 64-elem row r (16B-granule XOR key)
__device__ __forceinline__ int swz(int r, int d) {
    return ((d & ~7) ^ ((r & 7) << 3)) | (d & 7);
}

// ---------- kernel 1: enh + swizzled bf16 hi/lo codebook [k][64] ----------
__global__ __launch_bounds__(256) void prep_kernel(const float* __restrict__ e,
                                                   float* __restrict__ enh,
                                                   unsigned short* __restrict__ ehT,
                                                   unsigned short* __restrict__ elT,
                                                   float* __restrict__ sum,
                                                   unsigned* __restrict__ tick) {
    __shared__ unsigned short tH[64 * 64];   // 8KB [code_local][swz d]
    __shared__ unsigned short tL[64 * 64];
    __shared__ float ps[4 * 64];
    const int tid = threadIdx.x, wave = tid >> 6, lane = tid & 63;
    if (blockIdx.x == 0 && tid == 0) { *sum = 0.f; *tick = 0u; }
    const int k = blockIdx.x * 64 + lane;    // this thread's code
    float s2 = 0.f;
    short8 hh[2], ll[2];
#pragma unroll
    for (int g = 0; g < 2; ++g)
#pragma unroll
        for (int j = 0; j < 8; ++j) {
            const int d = wave * 16 + g * 8 + j;
            const float v = e[d * KK + k];   // lanes k-contiguous -> coalesced
            const unsigned short h = bf16_rne(v);
            hh[g][j] = (short)h;
            ll[g][j] = (short)bf16_rne(v - bf16_to_f(h));
            s2 = fmaf(v, v, s2);
        }
    ps[wave * 64 + lane] = s2;
#pragma unroll
    for (int g = 0; g < 2; ++g) {
        const int pos = lane * 64 + ((wave * 16 + g * 8) ^ ((k & 7) << 3));
        *(short8*)(tH + pos) = hh[g];
        *(short8*)(tL + pos) = ll[g];
    }
    __syncthreads();
    if (wave == 0) {
        const float t = ps[lane] + ps[64 + lane] + ps[128 + lane] + ps[192 + lane];
        enh[k] = 512.0f - 0.5f * t;
    }
    {
        const short8* srcH = (const short8*)tH;
        const short8* srcL = (const short8*)tL;
        short8* dstH = (short8*)(ehT + blockIdx.x * 64 * 64);
        short8* dstL = (short8*)(elT + blockIdx.x * 64 * 64);
        dstH[tid * 2]     = srcH[tid * 2];
        dstH[tid * 2 + 1] = srcH[tid * 2 + 1];
        dstL[tid * 2]     = srcL[tid * 2];
        dstL[tid * 2 + 1] = srcL[tid * 2 + 1];
    }
}

// ======================= WITHIN-RUN A/B (r8 method) =======================
// r13 (512-thr, 4 waves/SIMD, half traffic) = 59us full-grid, best so far.
// Remaining model: 16 per-tile {__syncthreads->vmcnt(0)} drains; compute
// window (~750ns/SIMD) < DMA fill under 512-block L2 contention. Counted
// vmcnt is neutral (r12); residency maxed at this traffic. Untested knob:
// BARRIER FREQUENCY. B processes 2 tiles per barrier (32KB DMA batches,
// 8 drains) at the SAME traffic and SAME 2-blocks/CU residency (68KB LDS,
// 136KB/CU) -> isolates drain-amortization cleanly (m132's BK=128 failure
// was an occupancy loss, absent here).

// ---------- kernel 2A: r13 body (control), blocks 0-255 ----------
__global__ __launch_bounds__(512) void vq_gemm_a(const float* __restrict__ x,
                                                 const float* __restrict__ e,
                                                 const float* __restrict__ enh,
                                                 const unsigned short* __restrict__ ehT,
                                                 const unsigned short* __restrict__ elT,
                                                 float* __restrict__ out,
                                                 float* __restrict__ sum,
                                                 unsigned* __restrict__ tick) {
    __shared__ __align__(16) char ebuf[2 * 16384];   // 32KB double buffer
    __shared__ float enh_lds[1024];                  // 4KB bias table

    unsigned short* xbh = (unsigned short*)ebuf;
    unsigned short* xbl = (unsigned short*)(ebuf + 16384);
    int*   ks  = (int*)ebuf;
    float* xp  = (float*)(ks + 128);
    int*   rl  = (int*)(xp + 64);
    int*   rn  = rl + 128;
    float* rv  = (float*)(rn + 1);
    int*   ri  = (int*)(rv + 8);
    float* red = (float*)(ri + 8);

    const int tid = threadIdx.x;
    const int wave = tid >> 6, lane = tid & 63;
    const int n0 = blockIdx.x * 128;
    const int b = n0 >> 12;
    const int hw0 = n0 & 4095;

    const char* ehTb = (const char*)ehT;
    const char* elTb = (const char*)elT;

    *(float2*)(enh_lds + tid * 2) = *(const float2*)(enh + tid * 2);

    {
        const int p = tid & 127, dg = tid >> 7;
        const float* xs = x + ((b * DD + dg * 16) << 12) + hw0 + p;
        float xv[16];
#pragma unroll
        for (int s = 0; s < 16; ++s) xv[s] = xs[s << 12];
#pragma unroll
        for (int g = 0; g < 2; ++g) {
            short8 hh, ll;
#pragma unroll
            for (int j = 0; j < 8; ++j) {
                const float f = xv[g * 8 + j];
                const unsigned short h = bf16_rne(f);
                hh[j] = (short)h;
                ll[j] = (short)bf16_rne(f - bf16_to_f(h));
            }
            const int d0 = dg * 16 + g * 8;
            const int pos = p * 64 + (d0 ^ ((p & 7) << 3));
            *(short8*)(xbh + pos) = hh;
            *(short8*)(xbl + pos) = ll;
        }
    }
    __syncthreads();

    const int ln15 = lane & 15, q8 = (lane >> 4) * 8;
    const int wp = wave * 16;

    short8 ah[2], al[2];
#pragma unroll
    for (int kc = 0; kc < 2; ++kc) {
        const int pp = wp + ln15;
        const int pos = pp * 64 + ((kc * 32 + q8) ^ ((pp & 7) << 3));
        ah[kc] = *(const short8*)(xbh + pos);
        al[kc] = *(const short8*)(xbl + pos);
    }
    __syncthreads();

    const int wsel = (wave < 4) ? wave : (wave - 4);
    const char* srcTab = (wave < 4) ? ehTb : elTb;
    const int dofs = ((wave < 4) ? 0 : 8192) + wsel * 2048;

    {
        const char* sb = srcTab + wsel * 2048 + lane * 16;
        gld_lds16(sb,        ebuf + dofs);
        gld_lds16(sb + 1024, ebuf + dofs + 1024);
    }

    unsigned v1u[4], v2u[4];
#pragma unroll
    for (int r = 0; r < 4; ++r) { v1u[r] = 0u; v2u[r] = 0u; }

    for (int kt = 0; kt < 16; ++kt) {
        __syncthreads();
        if (kt < 15) {
            const int nkt = kt + 1;
            char* db = ebuf + (nkt & 1) * 16384;
            const char* sb = srcTab + nkt * 8192 + wsel * 2048 + lane * 16;
            gld_lds16(sb,        db + dofs);
            gld_lds16(sb + 1024, db + dofs + 1024);
        }
        const unsigned short* ebH = (const unsigned short*)(ebuf + (kt & 1) * 16384);
        const unsigned short* ebL = ebH + 4096;

        f32x4 acc[4];
#pragma unroll
        for (int cf = 0; cf < 4; ++cf) {
            const float ec = enh_lds[kt * 64 + cf * 16 + ln15];
            acc[cf] = (f32x4){ec, ec, ec, ec};
        }

#pragma unroll
        for (int kc = 0; kc < 2; ++kc) {
            short8 bh[4], bl[4];
#pragma unroll
            for (int cf = 0; cf < 4; ++cf) {
                const int c = cf * 16 + ln15;
                const int pos = c * 64 + ((kc * 32 + q8) ^ ((c & 7) << 3));
                bh[cf] = *(const short8*)(ebH + pos);
                bl[cf] = *(const short8*)(ebL + pos);
            }
#pragma unroll
            for (int cf = 0; cf < 4; ++cf) {
                acc[cf] = __builtin_amdgcn_mfma_f32_16x16x32_bf16(al[kc], bh[cf], acc[cf], 0, 0, 0);
                acc[cf] = __builtin_amdgcn_mfma_f32_16x16x32_bf16(ah[kc], bl[cf], acc[cf], 0, 0, 0);
                acc[cf] = __builtin_amdgcn_mfma_f32_16x16x32_bf16(ah[kc], bh[cf], acc[cf], 0, 0, 0);
            }
        }

#pragma unroll
        for (int reg = 0; reg < 4; ++reg) {
            const unsigned k0 = (__float_as_uint(acc[0][reg]) | 63u) ^ (unsigned)(kt * 4 + 0);
            const unsigned k1 = (__float_as_uint(acc[1][reg]) | 63u) ^ (unsigned)(kt * 4 + 1);
            const unsigned k2 = (__float_as_uint(acc[2][reg]) | 63u) ^ (unsigned)(kt * 4 + 2);
            const unsigned k3 = (__float_as_uint(acc[3][reg]) | 63u) ^ (unsigned)(kt * 4 + 3);
            unsigned a = umax(k0, k1), bb = umin(k0, k1);
            v2u[reg] = umax(umax(v2u[reg], umin(v1u[reg], a)), bb);
            v1u[reg] = umax(v1u[reg], a);
            a = umax(k2, k3); bb = umin(k2, k3);
            v2u[reg] = umax(umax(v2u[reg], umin(v1u[reg], a)), bb);
            v1u[reg] = umax(v1u[reg], a);
        }
    }

    __syncthreads();
    if (tid == 0) *rn = 0;
    __syncthreads();

#pragma unroll
    for (int r = 0; r < 4; ++r) {
        const unsigned c6 = 63u - (v1u[r] & 63u);
        int col = (int)(c6 >> 2) * 64 + (int)(c6 & 3) * 16 + ln15;
        float val = __uint_as_float(v1u[r] & ~63u);
        float sec = __uint_as_float(v2u[r] & ~63u);
#pragma unroll
        for (int msk = 1; msk < 16; msk <<= 1) {
            const float ov = __shfl_xor(val, msk);
            const int oc = __shfl_xor(col, msk);
            const float os = __shfl_xor(sec, msk);
            sec = fmaxf(fmaxf(sec, os), fminf(val, ov));
            const bool t = (ov > val) || (ov == val && oc < col);
            val = t ? ov : val;
            col = t ? oc : col;
        }
        if (ln15 == 0) {
            const int qq = lane >> 4;
            const int pt = wp + qq * 4 + r;
            ks[pt] = col;
            if (val - sec < MARGIN_S) {
                const int w = atomicAdd(rn, 1);
                rl[w] = pt;
            }
        }
    }
    __syncthreads();

    const int lcnt = *rn;
    for (int it = 0; it < lcnt; ++it) {
        const int pr = rl[it];
        if (tid < 64) xp[tid] = x[((b * DD + tid) << 12) + hw0 + pr];
        __syncthreads();
        float bs = -3.4e38f;
        int bi2 = 0;
        if (tid < 256) {
            float d0 = 0.f, d1 = 0.f, d2 = 0.f, d3 = 0.f;
#pragma unroll 8
            for (int dd = 0; dd < DD; ++dd) {
                const float xd = xp[dd];
                const float4 ev = *(const float4*)(e + dd * KK + tid * 4);
                d0 = fmaf(xd, ev.x, d0);
                d1 = fmaf(xd, ev.y, d1);
                d2 = fmaf(xd, ev.z, d2);
                d3 = fmaf(xd, ev.w, d3);
            }
            const float4 ea = *(const float4*)(enh + tid * 4);
            bs = d0 + ea.x;
            bi2 = tid * 4;
            if (d1 + ea.y > bs) { bs = d1 + ea.y; bi2 = tid * 4 + 1; }
            if (d2 + ea.z > bs) { bs = d2 + ea.z; bi2 = tid * 4 + 2; }
            if (d3 + ea.w > bs) { bs = d3 + ea.w; bi2 = tid * 4 + 3; }
        }
#pragma unroll
        for (int m = 1; m < 64; m <<= 1) {
            const float ov = __shfl_xor(bs, m, 64);
            const int oi = __shfl_xor(bi2, m, 64);
            if (ov > bs || (ov == bs && oi < bi2)) { bs = ov; bi2 = oi; }
        }
        if (lane == 0) { rv[wave] = bs; ri[wave] = bi2; }
        __syncthreads();
        if (tid == 0) {
            float gs = rv[0];
            int gi = ri[0];
#pragma unroll
            for (int t2 = 1; t2 < 8; ++t2)
                if (rv[t2] > gs || (rv[t2] == gs && ri[t2] < gi)) { gs = rv[t2]; gi = ri[t2]; }
            ks[pr] = gi;
        }
        __syncthreads();
    }

    if (tid < 128) out[OFF_IDX + n0 + tid] = (float)ks[tid];

    {
        const int pe = tid & 127, dh = tid >> 7;
        const int kp = ks[pe];
        float lacc = 0.f;
#pragma unroll
        for (int s = 0; s < 16; ++s) {
            const int d = dh * 16 + s;
            const float qv = e[d * KK + kp];
            const float xv = x[((b * DD + d) << 12) + hw0 + pe];
            out[((b * DD + d) << 12) + hw0 + pe] = qv;
            const float df = xv - qv;
            lacc = fmaf(df, df, lacc);
        }
#pragma unroll
        for (int off = 32; off > 0; off >>= 1) lacc += __shfl_down(lacc, off, 64);
        if (lane == 0) red[wave] = lacc;
    }
    __syncthreads();
    if (tid == 0) {
        float bsum = red[0];
#pragma unroll
        for (int w2 = 1; w2 < 8; ++w2) bsum += red[w2];
        atomicAdd(sum, bsum);
        __threadfence();
        const unsigned old = atomicAdd(tick, 1u);
        if (old == (unsigned)(NBLK_TOTAL - 1)) {
            const float s = atomicAdd(sum, 0.0f);
            const float m = s * (1.0f / (float)TOTAL);
            out[OFF_L1] = m;
            out[OFF_L2] = m;
        }
    }
}

// ---------- kernel 2B: r13 + 2 tiles per barrier, blocks 256-511 ----------
// Same math; buffers are 32KB (two 16KB tile-slots), DMA issues BOTH tiles
// of the next pair per step (4 ops/wave), 8 barriers instead of 16. LDS =
// 64KB ebuf + 4KB enh = 68KB -> 2 blocks/CU (136KB), residency unchanged
// vs A -> isolates drain-amortization.
__global__ __launch_bounds__(512) void vq_gemm_b(const float* __restrict__ x,
                                                 const float* __restrict__ e,
                                                 const float* __restrict__ enh,
                                                 const unsigned short* __restrict__ ehT,
                                                 const unsigned short* __restrict__ elT,
                                                 float* __restrict__ out,
                                                 float* __restrict__ sum,
                                                 unsigned* __restrict__ tick) {
    __shared__ __align__(16) char ebuf[2 * 32768];   // 64KB: 2 buffers x 2 tile-slots
    __shared__ float enh_lds[1024];                  // 4KB bias table

    unsigned short* xbh = (unsigned short*)ebuf;            // prologue staging
    unsigned short* xbl = (unsigned short*)(ebuf + 16384);
    int*   ks  = (int*)ebuf;            // post-loop aliases
    float* xp  = (float*)(ks + 128);
    int*   rl  = (int*)(xp + 64);
    int*   rn  = rl + 128;
    float* rv  = (float*)(rn + 1);
    int*   ri  = (int*)(rv + 8);
    float* red = (float*)(ri + 8);

    const int tid = threadIdx.x;
    const int wave = tid >> 6, lane = tid & 63;
    const int n0 = (blockIdx.x + 256) * 128;   // second half of points
    const int b = n0 >> 12;
    const int hw0 = n0 & 4095;

    const char* ehTb = (const char*)ehT;
    const char* elTb = (const char*)elT;

    *(float2*)(enh_lds + tid * 2) = *(const float2*)(enh + tid * 2);

    {
        const int p = tid & 127, dg = tid >> 7;
        const float* xs = x + ((b * DD + dg * 16) << 12) + hw0 + p;
        float xv[16];
#pragma unroll
        for (int s = 0; s < 16; ++s) xv[s] = xs[s << 12];
#pragma unroll
        for (int g = 0; g < 2; ++g) {
            short8 hh, ll;
#pragma unroll
            for (int j = 0; j < 8; ++j) {
                const float f = xv[g * 8 + j];
                const unsigned short h = bf16_rne(f);
                hh[j] = (short)h;
                ll[j] = (short)bf16_rne(f - bf16_to_f(h));
            }
            const int d0 = dg * 16 + g * 8;
            const int pos = p * 64 + (d0 ^ ((p & 7) << 3));
            *(short8*)(xbh + pos) = hh;
            *(short8*)(xbl + pos) = ll;
        }
    }
    __syncthreads();

    const int ln15 = lane & 15, q8 = (lane >> 4) * 8;
    const int wp = wave * 16;

    short8 ah[2], al[2];
#pragma unroll
    for (int kc = 0; kc < 2; ++kc) {
        const int pp = wp + ln15;
        const int pos = pp * 64 + ((kc * 32 + q8) ^ ((pp & 7) << 3));
        ah[kc] = *(const short8*)(xbh + pos);
        al[kc] = *(const short8*)(xbl + pos);
    }
    __syncthreads();   // frags in regs everywhere; ebuf free for tile DMA

    const int wsel = (wave < 4) ? wave : (wave - 4);
    const char* srcTab = (wave < 4) ? ehTb : elTb;
    const int dofs = ((wave < 4) ? 0 : 8192) + wsel * 2048;

    // DMA(pair 0) = tiles 0,1 into buf0's two slots
#pragma unroll
    for (int s = 0; s < 2; ++s) {
        const char* sb = srcTab + s * 8192 + wsel * 2048 + lane * 16;
        gld_lds16(sb,        ebuf + s * 16384 + dofs);
        gld_lds16(sb + 1024, ebuf + s * 16384 + dofs + 1024);
    }

    unsigned v1u[4], v2u[4];
#pragma unroll
    for (int r = 0; r < 4; ++r) { v1u[r] = 0u; v2u[r] = 0u; }

    for (int step = 0; step < 8; ++step) {
        __syncthreads();   // drains pair-step DMA + all waves done with step-1
        if (step < 7) {    // stream pair step+1 (tiles 2*step+2, 2*step+3)
            char* db = ebuf + ((step + 1) & 1) * 32768;
#pragma unroll
            for (int s = 0; s < 2; ++s) {
                const int t = 2 * step + 2 + s;
                const char* sb = srcTab + t * 8192 + wsel * 2048 + lane * 16;
                gld_lds16(sb,        db + s * 16384 + dofs);
                gld_lds16(sb + 1024, db + s * 16384 + dofs + 1024);
            }
        }
        const char* cbuf = ebuf + (step & 1) * 32768;

#pragma unroll
        for (int s = 0; s < 2; ++s) {
            const int kt = 2 * step + s;
            const unsigned short* ebH = (const unsigned short*)(cbuf + s * 16384);
            const unsigned short* ebL = ebH + 4096;

            f32x4 acc[4];
#pragma unroll
            for (int cf = 0; cf < 4; ++cf) {
                const float ec = enh_lds[kt * 64 + cf * 16 + ln15];
                acc[cf] = (f32x4){ec, ec, ec, ec};
            }

#pragma unroll
            for (int kc = 0; kc < 2; ++kc) {
                short8 bh[4], bl[4];
#pragma unroll
                for (int cf = 0; cf < 4; ++cf) {
                    const int c = cf * 16 + ln15;
                    const int pos = c * 64 + ((kc * 32 + q8) ^ ((c & 7) << 3));
                    bh[cf] = *(const short8*)(ebH + pos);
                    bl[cf] = *(const short8*)(ebL + pos);
                }
#pragma unroll
                for (int cf = 0; cf < 4; ++cf) {
                    acc[cf] = __builtin_amdgcn_mfma_f32_16x16x32_bf16(al[kc], bh[cf], acc[cf], 0, 0, 0);
                    acc[cf] = __builtin_amdgcn_mfma_f32_16x16x32_bf16(ah[kc], bl[cf], acc[cf], 0, 0, 0);
                    acc[cf] = __builtin_amdgcn_mfma_f32_16x16x32_bf16(ah[kc], bh[cf], acc[cf], 0, 0, 0);
                }
            }

#pragma unroll
            for (int reg = 0; reg < 4; ++reg) {
                const unsigned k0 = (__float_as_uint(acc[0][reg]) | 63u) ^ (unsigned)(kt * 4 + 0);
                const unsigned k1 = (__float_as_uint(acc[1][reg]) | 63u) ^ (unsigned)(kt * 4 + 1);
                const unsigned k2 = (__float_as_uint(acc[2][reg]) | 63u) ^ (unsigned)(kt * 4 + 2);
                const unsigned k3 = (__float_as_uint(acc[3][reg]) | 63u) ^ (unsigned)(kt * 4 + 3);
                unsigned a = umax(k0, k1), bb = umin(k0, k1);
                v2u[reg] = umax(umax(v2u[reg], umin(v1u[reg], a)), bb);
                v1u[reg] = umax(v1u[reg], a);
                a = umax(k2, k3); bb = umin(k2, k3);
                v2u[reg] = umax(umax(v2u[reg], umin(v1u[reg], a)), bb);
                v1u[reg] = umax(v1u[reg], a);
            }
        }
    }

    __syncthreads();   // all waves done with last pair -> ebuf aliases safe
    if (tid == 0) *rn = 0;
    __syncthreads();

#pragma unroll
    for (int r = 0; r < 4; ++r) {
        const unsigned c6 = 63u - (v1u[r] & 63u);
        int col = (int)(c6 >> 2) * 64 + (int)(c6 & 3) * 16 + ln15;
        float val = __uint_as_float(v1u[r] & ~63u);
        float sec = __uint_as_float(v2u[r] & ~63u);
#pragma unroll
        for (int msk = 1; msk < 16; msk <<= 1) {
            const float ov = __shfl_xor(val, msk);
            const int oc = __shfl_xor(col, msk);
            const float os = __shfl_xor(sec, msk);
            sec = fmaxf(fmaxf(sec, os), fminf(val, ov));
            const bool t = (ov > val) || (ov == val && oc < col);
            val = t ? ov : val;
            col = t ? oc : col;
        }
        if (ln15 == 0) {
            const int qq = lane >> 4;
            const int pt = wp + qq * 4 + r;
            ks[pt] = col;
            if (val - sec < MARGIN_S) {
                const int w = atomicAdd(rn, 1);
                rl[w] = pt;
            }
        }
    }
    __syncthreads();

    const int lcnt = *rn;
    for (int it = 0; it < lcnt; ++it) {
        const int pr = rl[it];
        if (tid < 64) xp[tid] = x[((b * DD + tid) << 12) + hw0 + pr];
        __syncthreads();
        float bs = -3.4e38f;
        int bi2 = 0;
        if (tid < 256) {
            float d0 = 0.f, d1 = 0.f, d2 = 0.f, d3 = 0.f;
#pragma unroll 8
            for (int dd = 0; dd < DD; ++dd) {
                const float xd = xp[dd];
                const float4 ev = *(const float4*)(e + dd * KK + tid * 4);
                d0 = fmaf(xd, ev.x, d0);
                d1 = fmaf(xd, ev.y, d1);
                d2 = fmaf(xd, ev.z, d2);
                d3 = fmaf(xd, ev.w, d3);
            }
            const float4 ea = *(const float4*)(enh + tid * 4);
            bs = d0 + ea.x;
            bi2 = tid * 4;
            if (d1 + ea.y > bs) { bs = d1 + ea.y; bi2 = tid * 4 + 1; }
            if (d2 + ea.z > bs) { bs = d2 + ea.z; bi2 = tid * 4 + 2; }
            if (d3 + ea.w > bs) { bs = d3 + ea.w; bi2 = tid * 4 + 3; }
        }
#pragma unroll
        for (int m = 1; m < 64; m <<= 1) {
            const float ov = __shfl_xor(bs, m, 64);
            const int oi = __shfl_xor(bi2, m, 64);
            if (ov > bs || (ov == bs && oi < bi2)) { bs = ov; bi2 = oi; }
        }
        if (lane == 0) { rv[wave] = bs; ri[wave] = bi2; }
        __syncthreads();
        if (tid == 0) {
            float gs = rv[0];
            int gi = ri[0];
#pragma unroll
            for (int t2 = 1; t2 < 8; ++t2)
                if (rv[t2] > gs || (rv[t2] == gs && ri[t2] < gi)) { gs = rv[t2]; gi = ri[t2]; }
            ks[pr] = gi;
        }
        __syncthreads();
    }

    if (tid < 128) out[OFF_IDX + n0 + tid] = (float)ks[tid];

    {
        const int pe = tid & 127, dh = tid >> 7;
        const int kp = ks[pe];
        float lacc = 0.f;
#pragma unroll
        for (int s = 0; s < 16; ++s) {
            const int d = dh * 16 + s;
            const float qv = e[d * KK + kp];
            const float xv = x[((b * DD + d) << 12) + hw0 + pe];
            out[((b * DD + d) << 12) + hw0 + pe] = qv;
            const float df = xv - qv;
            lacc = fmaf(df, df, lacc);
        }
#pragma unroll
        for (int off = 32; off > 0; off >>= 1) lacc += __shfl_down(lacc, off, 64);
        if (lane == 0) red[wave] = lacc;
    }
    __syncthreads();
    if (tid == 0) {
        float bsum = red[0];
#pragma unroll
        for (int w2 = 1; w2 < 8; ++w2) bsum += red[w2];
        atomicAdd(sum, bsum);
        __threadfence();
        const unsigned old = atomicAdd(tick, 1u);
        if (old == (unsigned)(NBLK_TOTAL - 1)) {
            const float s = atomicAdd(sum, 0.0f);
            const float m = s * (1.0f / (float)TOTAL);
            out[OFF_L1] = m;
            out[OFF_L2] = m;
        }
    }
}

extern "C" void kernel_launch(void* const* d_in, const int* in_sizes, int n_in,
                              void* d_out, int out_size, void* d_ws, size_t ws_size,
                              hipStream_t stream) {
    const float* x = (const float*)d_in[0];      // [16,64,64,64]
    const float* e = (const float*)d_in[1];      // [64,1024]
    float* out = (float*)d_out;

    float* sum = (float*)d_ws;
    unsigned* tick = (unsigned*)d_ws + 2;
    float* enh = (float*)d_ws + WS_ENH_F;
    unsigned short* ehT = (unsigned short*)((char*)d_ws + WS_EHT_BYTE);
    unsigned short* elT = (unsigned short*)((char*)d_ws + WS_ELT_BYTE);

    prep_kernel<<<KK / 64, 256, 0, stream>>>(e, enh, ehT, elT, sum, tick);
    vq_gemm_a<<<256, 512, 0, stream>>>(x, e, enh, ehT, elT, out, sum, tick);
    vq_gemm_b<<<256, 512, 0, stream>>>(x, e, enh, ehT, elT, out, sum, tick);
}